// Round 9
// baseline (223.803 us; speedup 1.0000x reference)
//
#include <hip/hip_runtime.h>
#include <hip/hip_bf16.h>
#include <math.h>

#define B_ 8
#define P_ 24
#define N_ 1024
#define C_ 16
#define D_ 256
#define K_ 13

// workspace offsets (in floats)
#define OFF_SM   0          // spatial_mean: 192*16
#define OFF_ATT  8192       // att: 8*24
#define OFF_GAM  9216       // gamma: 8*32 (re[13] @ +0, im[13] @ +16)
#define OFF_TE   12288      // te_fold: 192*256
#define OFF_ZWC  122880     // zw_const: 8*256
#define OFF_AB   126976     // ABt bf16 FRAGMENT order [k][wave][half][lane][8]
#define OFF_BC   266240     // bias_comb: 13*256
#define OFF_DD   270336     // Dt bf16 FRAGMENT order [k][wave][s][half][lane][8]
#define OFF_W2E  696320     // W2ext bf16 [q2][288]
#define OFF_XC   1126400    // Xhat bf16 FRAGMENT order [b][k][nt32][half][lane][8]
#define OFF_XW   2830336    // xw fp32: 8*1024*16
#define OFF_ABP  3000000    // AB partials fp32 [k][et][32ch][256o]
#define OFF_C1P  3900000    // c1 REDUCED fp32 [b][k][256]
#define OFF_DLP  3930112    // d_lag partials: [b][4lag][24t][16chunk] = 12288
#define OFF_PACC 4194304    // GEMM1 split-k partials fp32 [kh=4][b][nt32][wave][4][256]
#define KH_STRIDE 2097152   // 8*32*8*4*256

typedef unsigned short ushort_t;
typedef __bf16 bf16x8 __attribute__((ext_vector_type(8)));
typedef float f32x4 __attribute__((ext_vector_type(4)));
typedef unsigned short ushort4_t __attribute__((ext_vector_type(4)));

__device__ __forceinline__ float gelu_f(float v) {
    return 0.5f * v * (1.0f + erff(v * 0.70710678118654752440f));
}
__device__ __forceinline__ float softplus_f(float z) {
    return fmaxf(z, 0.0f) + log1pf(expf(-fabsf(z)));
}
__device__ __forceinline__ ushort_t f2bf(float f) {
    union { float f; unsigned u; } v; v.f = f;
    unsigned r = v.u + 0x7fffu + ((v.u >> 16) & 1u);
    return (ushort_t)(r >> 16);
}
__device__ __forceinline__ float bf2f(ushort_t h) {
    union { unsigned u; float f; } v; v.u = ((unsigned)h) << 16;
    return v.f;
}
__device__ __forceinline__ float4 f4add(float4 a, float4 b) {
    a.x += b.x; a.y += b.y; a.z += b.z; a.w += b.w; return a;
}
__device__ __forceinline__ ushort4_t pack4(f32x4 v, float4 c) {
    ushort4_t w;
    w.x = f2bf(gelu_f(v[0] + c.x));
    w.y = f2bf(gelu_f(v[1] + c.y));
    w.z = f2bf(gelu_f(v[2] + c.z));
    w.w = f2bf(gelu_f(v[3] + c.w));
    return w;
}
__device__ __forceinline__ ushort4_t pack4f(float4 v, float4 c) {
    ushort4_t w;
    w.x = f2bf(gelu_f(v.x + c.x));
    w.y = f2bf(gelu_f(v.y + c.y));
    w.z = f2bf(gelu_f(v.z + c.z));
    w.w = f2bf(gelu_f(v.w + c.w));
    return w;
}

// ==== A: prep_d(832, dbuf) + xhat(512) + ab_part(104) + mean(192) + lag(128)
//      + w2e(256) = 2024 blocks, longest-first ====
__global__ void k_A(const float* __restrict__ x, const float* __restrict__ in_proj_w,
                    const float* __restrict__ sfe_w1, const float* __restrict__ sfe_w2,
                    const float* __restrict__ sfe_b2, const float* __restrict__ comb_w1,
                    const float* __restrict__ comb_w2, float* __restrict__ ws) {
    __shared__ __align__(16) char smem[8448];
    int bx = blockIdx.x, tid = threadIdx.x;
    if (bx < 832) {
        // prep_d: 32i x 32q tiles (8x8 x 13k), double-buffered As/Bs
        int j = bx;
        int qt0 = (j & 7) * 32, it3 = (j >> 3) & 7, k = j >> 6;
        int it0 = it3 * 32;
        float* sm0 = (float*)smem;   // 2 x (As 32*17 + Bs 16*32) = 2112 floats
        int tq = tid & 15, ti = tid >> 4;
        float acc[2][2];
        acc[0][0] = 0.f; acc[0][1] = 0.f; acc[1][0] = 0.f; acc[1][1] = 0.f;
        float bias = 0.f;
        {   // preload step 0 -> buf 0
            float* As = sm0; float* Bs = sm0 + 544;
            #pragma unroll
            for (int u = 0; u < 2; u++) {
                int idx = u * 256 + tid;
                int i = idx >> 4, o = idx & 15;
                As[i * 17 + o] = sfe_w2[((long)(k * 256 + it0 + i) << 8) + o];
            }
            #pragma unroll
            for (int u = 0; u < 2; u++) {
                int idx = u * 256 + tid;
                int o = idx >> 5, q = idx & 31;
                Bs[o * 32 + q] = comb_w1[((long)(k * 256 + o) << 8) + qt0 + q];
            }
        }
        __syncthreads();
        for (int step = 0; step < 16; step++) {
            int cur = step & 1;
            float* As = sm0 + cur * 1056;
            float* Bs = As + 544;
            if (step + 1 < 16) {
                int ob2 = (step + 1) * 16;
                float* An = sm0 + (cur ^ 1) * 1056;
                float* Bn = An + 544;
                #pragma unroll
                for (int u = 0; u < 2; u++) {
                    int idx = u * 256 + tid;
                    int i = idx >> 4, o = idx & 15;
                    An[i * 17 + o] = sfe_w2[((long)(k * 256 + it0 + i) << 8) + ob2 + o];
                }
                #pragma unroll
                for (int u = 0; u < 2; u++) {
                    int idx = u * 256 + tid;
                    int o = idx >> 5, q = idx & 31;
                    Bn[o * 32 + q] = comb_w1[((long)(k * 256 + ob2 + o) << 8) + qt0 + q];
                }
            }
            int ob = step * 16;
            if (it3 == 0 && tid < 32) {
                #pragma unroll
                for (int o = 0; o < 16; o++)
                    bias += sfe_b2[k * 256 + ob + o] * Bs[o * 32 + tid];
            }
            #pragma unroll 8
            for (int o = 0; o < 16; o++) {
                float2 bv = *(const float2*)&Bs[o * 32 + tq * 2];
                float a0 = As[(ti * 2 + 0) * 17 + o];
                float a1 = As[(ti * 2 + 1) * 17 + o];
                acc[0][0] += a0 * bv.x; acc[0][1] += a0 * bv.y;
                acc[1][0] += a1 * bv.x; acc[1][1] += a1 * bv.y;
            }
            __syncthreads();
        }
        ushort_t* dtp = (ushort_t*)(ws + OFF_DD);
        #pragma unroll
        for (int c = 0; c < 2; c++)
            #pragma unroll
            for (int r = 0; r < 2; r++) {
                int q = qt0 + tq * 2 + c, i = it0 + ti * 2 + r;
                int wv = q >> 5, hf = (q >> 4) & 1, l = q & 15;
                int s = i >> 5, qd = (i >> 3) & 3, jj = i & 7;
                long idx = ((((long)(k * 8 + wv) * 8 + s) * 2 + hf) * 64 + qd * 16 + l) * 8 + jj;
                dtp[idx] = f2bf(acc[r][c]);
            }
        if (it3 == 0 && tid < 32)
            ws[OFF_BC + k * 256 + qt0 + tid] = bias;
    } else if (bx < 1344) {
        // xhat DFT -> fragment-ordered xc2
        int j = bx - 832;
        int ntile = j & 63, b = j >> 6;
        float* ct = (float*)smem;
        float* st = ct + K_ * P_;
        int n = ntile * 16 + (tid >> 4), c = tid & 15;
        for (int i = tid; i < K_ * P_; i += 256) {
            int k = i / P_, t = i % P_;
            int r = (k * t) % P_;
            float ph = 6.283185307179586f * (float)r / (float)P_;
            ct[i] = cosf(ph);
            st[i] = sinf(ph);
        }
        __syncthreads();
        float re[K_], im[K_];
        #pragma unroll
        for (int k = 0; k < K_; k++) { re[k] = 0.f; im[k] = 0.f; }
        for (int t = 0; t < P_; t++) {
            float v = x[((long)(b * P_ + t) * N_ + n) * C_ + c];
            #pragma unroll
            for (int k = 0; k < K_; k++) {
                re[k] += ct[k * P_ + t] * v;
                im[k] -= st[k * P_ + t] * v;
            }
        }
        ushort_t* xcp = (ushort_t*)(ws + OFF_XC);
        int nt32 = n >> 5, halfn = (n >> 4) & 1, l15n = n & 15;
        int lre = ((c >> 3) * 16 + l15n) * 8 + (c & 7);
        int lim = ((2 + (c >> 3)) * 16 + l15n) * 8 + (c & 7);
        #pragma unroll
        for (int k = 0; k < K_; k++) {
            long base = ((((long)(b * K_ + k) * 32 + nt32) * 2 + halfn) * 64) * 8;
            xcp[base + lre] = f2bf(re[k]);
            xcp[base + lim] = f2bf(im[k]);
        }
    } else if (bx < 1448) {
        // ab_part
        int j = bx - 1344;
        int k = j >> 3, et = j & 7;
        int o = tid;
        float accA[C_], accB[C_];
        #pragma unroll
        for (int c = 0; c < C_; c++) { accA[c] = 0.f; accB[c] = 0.f; }
        const float* w1r = sfe_w1 + (long)k * 512 * 256;
        const float* w1i = w1r + 256 * 256;
        for (int e = et * 32; e < et * 32 + 32; e++) {
            float vr = w1r[e * 256 + o];
            float vi = w1i[e * 256 + o];
            #pragma unroll
            for (int c = 0; c < C_; c++) {
                float w = in_proj_w[c * 256 + e];
                accA[c] += w * vr;
                accB[c] += w * vi;
            }
        }
        float* abp = ws + OFF_ABP + (long)((k * 8 + et) * 32) * 256;
        #pragma unroll
        for (int c = 0; c < C_; c++) {
            abp[c * 256 + o] = accA[c];
            abp[(16 + c) * 256 + o] = accB[c];
        }
    } else if (bx < 1640) {
        // spatial mean
        float* lds = (float*)smem;
        int bt = bx - 1448;
        int c = tid & 15, ns = tid >> 4;
        const float* xp = x + (long)bt * (N_ * C_);
        float s = 0.f;
        for (int n = ns; n < N_; n += 16) s += xp[n * C_ + c];
        lds[tid] = s;
        __syncthreads();
        for (int st = 128; st >= 16; st >>= 1) {
            if (tid < st) lds[tid] += lds[tid + st];
            __syncthreads();
        }
        if (tid < 16) ws[OFF_SM + bt * 16 + tid] = lds[tid] * (1.0f / 1024.0f);
    } else if (bx < 1768) {
        // single-pass lag distances: 8b x 16 chunks, 4 cols/thread via float4
        int j = bx - 1640;
        int b = j >> 4, chunk = j & 15;
        int idx4 = (chunk << 8) + tid;    // float4 index in [0,4096)
        const float* xp = x + (long)b * (P_ * N_ * C_) + (idx4 << 2);
        float* sacc = (float*)smem;  // [4 waves][96]
        for (int i = tid; i < 384; i += 256) sacc[i] = 0.f;
        __syncthreads();
        int wave = tid >> 6, lane = tid & 63;
        float xh0[4] = {0.f,0.f,0.f,0.f}, xh1[4] = {0.f,0.f,0.f,0.f};
        float xr1[4] = {0.f,0.f,0.f,0.f}, xr2[4] = {0.f,0.f,0.f,0.f};
        float xr3[4] = {0.f,0.f,0.f,0.f}, xr4[4] = {0.f,0.f,0.f,0.f};
        float xr5[4] = {0.f,0.f,0.f,0.f}, xr6[4] = {0.f,0.f,0.f,0.f};
        #pragma unroll
        for (int t = 0; t < P_; t++) {
            float4 xq = *(const float4*)&xp[t * (N_ * C_)];
            float xv[4] = {xq.x, xq.y, xq.z, xq.w};
            float xr_t[4];
            #pragma unroll
            for (int j2 = 0; j2 < 4; j2++)
                xr_t[j2] = (t == 0) ? 0.f
                        : (t == 1) ? (xv[j2] - xh0[j2])
                        : (xv[j2] - (xv[j2] + xh0[j2] + xh1[j2]) * (1.0f / 3.0f));
            if (t >= 1) {
                float v0 = 0.f, v1 = 0.f, v2 = 0.f, v3 = 0.f;
                #pragma unroll
                for (int j2 = 0; j2 < 4; j2++) {
                    v0 += fabsf(xr_t[j2] - xr1[j2]);
                    if (t >= 2) v1 += fabsf(xr_t[j2] - xr2[j2]);
                    if (t >= 4) v2 += fabsf(xr_t[j2] - xr4[j2]);
                    if (t >= 6) v3 += fabsf(xr_t[j2] - xr6[j2]);
                }
                #pragma unroll
                for (int off = 32; off > 0; off >>= 1) {
                    v0 += __shfl_down(v0, off);
                    v1 += __shfl_down(v1, off);
                    v2 += __shfl_down(v2, off);
                    v3 += __shfl_down(v3, off);
                }
                if (lane == 0) {
                    float* sa = sacc + wave * 96 + t;
                    sa[0]  += v0;
                    sa[24] += v1;
                    sa[48] += v2;
                    sa[72] += v3;
                }
            }
            #pragma unroll
            for (int j2 = 0; j2 < 4; j2++) {
                xr6[j2] = xr5[j2]; xr5[j2] = xr4[j2]; xr4[j2] = xr3[j2];
                xr3[j2] = xr2[j2]; xr2[j2] = xr1[j2]; xr1[j2] = xr_t[j2];
                xh1[j2] = xh0[j2]; xh0[j2] = xv[j2];
            }
        }
        __syncthreads();
        if (tid < 96) {
            float s = sacc[tid] + sacc[96 + tid] + sacc[192 + tid] + sacc[288 + tid];
            int li = tid / 24, t = tid - li * 24;
            ws[OFF_DLP + ((b * 4 + li) * P_ + t) * 16 + chunk] = s;
        }
    } else {
        // W2ext
        int q2 = bx - 1768;
        ushort_t* w2e = (ushort_t*)(ws + OFF_W2E);
        for (int i = tid; i < 288; i += 256) {
            float v = 0.f;
            if (i < 256) v = comb_w2[(i << 8) + q2];
            else if (i < 272) v = in_proj_w[((i - 256) << 8) + q2] * (1.0f / 0.3f);
            w2e[q2 * 288 + i] = f2bf(v);
        }
    }
}

// ==== B: gating+gamma (8) + time_emb (192) + ab_red (26) = 226 blocks, 128 thr ====
__global__ void k_B(const float* __restrict__ pool_param,
                    const float* __restrict__ pe_w1, const float* __restrict__ pe_b1,
                    const float* __restrict__ pe_w2, const float* __restrict__ pe_b2,
                    const float* __restrict__ noise_w, const float* __restrict__ noise_b,
                    const float* __restrict__ in_proj_b, float* __restrict__ ws) {
    __shared__ float sm[256];
    int bx = blockIdx.x, tid = threadIdx.x;
    if (bx < 8) {
        int b = bx;
        float* d = sm; float* ad = sm + 96; float* med = sm + 192; float* mad = sm + 196;
        float* attb = sm + 200; float* gbuf = sm + 224;
        int li = tid / P_, t = tid - li * P_;
        bool active = tid < 4 * P_;
        if (active) {
            const float* dp = ws + OFF_DLP + ((b * 4 + li) * P_ + t) * 16;
            float4 q0 = *(const float4*)&dp[0];
            float4 q1 = *(const float4*)&dp[4];
            float4 q2 = *(const float4*)&dp[8];
            float4 q3 = *(const float4*)&dp[12];
            float s = q0.x + q0.y + q0.z + q0.w + q1.x + q1.y + q1.z + q1.w
                    + q2.x + q2.y + q2.z + q2.w + q3.x + q3.y + q3.z + q3.w;
            d[li * P_ + t] = s * (1.0f / (N_ * C_));
        }
        __syncthreads();
        if (active) {
            float v = d[li * P_ + t];
            int rank = 0;
            #pragma unroll
            for (int jj = 0; jj < P_; jj++) {
                float dj = d[li * P_ + jj];
                rank += (dj < v || (dj == v && jj < t)) ? 1 : 0;
            }
            if (rank == 11) med[li] = v;
        }
        __syncthreads();
        if (active) ad[li * P_ + t] = fabsf(d[li * P_ + t] - med[li]);
        __syncthreads();
        if (active) {
            float v = ad[li * P_ + t];
            int rank = 0;
            #pragma unroll
            for (int jj = 0; jj < P_; jj++) {
                float dj = ad[li * P_ + jj];
                rank += (dj < v || (dj == v && jj < t)) ? 1 : 0;
            }
            if (rank == 11) mad[li] = v;
        }
        __syncthreads();
        if (active) {
            float z = (d[li * P_ + t] - med[li]) / (mad[li] * 1.4826f + 1e-6f);
            ad[li * P_ + t] = softplus_f(z);
        }
        __syncthreads();
        if (tid == 0) {
            float g[P_];
            #pragma unroll
            for (int tt = 0; tt < P_; tt++)
                g[tt] = 0.25f * (ad[tt] + ad[P_ + tt] + ad[2 * P_ + tt] + ad[3 * P_ + tt]);
            float c = g[0];
            gbuf[0] = g[0];
            for (int tt = 1; tt < P_; tt++) { c = 0.6f * c + 0.4f * g[tt]; gbuf[tt] = c; }
            float mean = 0.f;
            for (int tt = 0; tt < P_; tt++) mean += gbuf[tt];
            mean *= (1.0f / P_);
            float gate[P_];
            #pragma unroll
            for (int tt = 0; tt < P_; tt++) gate[tt] = 1.0f / (1.0f + expf(-1.5f * (gbuf[tt] - mean)));
            float m = -1e30f;
            float pp[P_];
            #pragma unroll
            for (int tt = 0; tt < P_; tt++) { pp[tt] = pool_param[tt]; m = fmaxf(m, pp[tt]); }
            float ssum = 0.f;
            #pragma unroll
            for (int tt = 0; tt < P_; tt++) { pp[tt] = expf(pp[tt] - m); ssum += pp[tt]; }
            float m2 = -1e30f;
            #pragma unroll
            for (int tt = 0; tt < P_; tt++) { pp[tt] = (pp[tt] / ssum) * (1.0f + gate[tt]); m2 = fmaxf(m2, pp[tt]); }
            float s2 = 0.f;
            #pragma unroll
            for (int tt = 0; tt < P_; tt++) { pp[tt] = expf(pp[tt] - m2); s2 += pp[tt]; }
            #pragma unroll
            for (int tt = 0; tt < P_; tt++) {
                float a = pp[tt] / s2;
                ws[OFF_ATT + b * P_ + tt] = a;
                attb[tt] = a;
            }
        }
        __syncthreads();
        if (tid < K_) {
            int k = tid;
            float cre = 0.f, cim = 0.f;
            for (int t2 = 0; t2 < P_; t2++) {
                int r = (k * t2) % P_;
                float ph = 6.283185307179586f * (float)r / (float)P_;
                float a = attb[t2];
                cre += a * cosf(ph);
                cim += a * sinf(ph);
            }
            float w = (k == 0 || k == 12) ? 1.0f : 2.0f;
            ws[OFF_GAM + b * 32 + k] = (w / 24.0f) * cre;
            ws[OFF_GAM + b * 32 + 16 + k] = -(w / 24.0f) * cim;
        }
    } else if (bx < 200) {
        int bt = bx - 8;
        int t = bt % P_;
        int k = tid >> 6, o = tid & 63;
        float* p1e = sm;
        float period = (k == 0) ? 24.0f : 72.0f;
        float ph = 6.283185307179586f * (float)t / period;
        float sv = sinf(ph), cv = cosf(ph);
        float v = sv * pe_w1[(k * 2 + 0) * 64 + o] + cv * pe_w1[(k * 2 + 1) * 64 + o] + pe_b1[k * 64 + o];
        p1e[tid] = gelu_f(v);
        __syncthreads();
        float acc = pe_b2[k * 64 + o];
        for (int i = 0; i < 64; i++) acc += p1e[k * 64 + i] * pe_w2[(k * 64 + i) * 64 + o];
        ws[OFF_TE + bt * D_ + tid] = acc + in_proj_b[tid];
        float nacc = noise_b[tid];
        for (int c = 0; c < C_; c++) nacc += ws[OFF_SM + bt * C_ + c] * noise_w[c * 128 + tid];
        ws[OFF_TE + bt * D_ + 128 + tid] = nacc + in_proj_b[128 + tid];
    } else {
        // ab_red: reduce AB partials -> ABt fragment order (26 blocks x 128 thr)
        int j = bx - 200;
        int k = j >> 1, o = ((j & 1) << 7) + tid;
        ushort_t* abt = (ushort_t*)(ws + OFF_AB);
        const float* base = ws + OFF_ABP + (long)(k * 8 * 32) * 256;
        int wv = o >> 5, hf = (o >> 4) & 1, l = o & 15;
        long obase = (((long)(k * 8 + wv) * 2 + hf) * 64) * 8;
        #pragma unroll
        for (int ch = 0; ch < 32; ch++) {
            float s = 0.f;
            #pragma unroll
            for (int et = 0; et < 8; et++) s += base[(et * 32 + ch) * 256 + o];
            abt[obase + ((ch >> 3) * 16 + l) * 8 + (ch & 7)] = f2bf(s);
        }
    }
}

// ==== D: c1 with INLINE Fte-DFT (104) + xw (512) + te_reduce (8) = 624 blocks ====
__global__ void k_D(const float* __restrict__ sfe_w1, const float* __restrict__ sfe_b1,
                    const float* __restrict__ in_proj_b, float* __restrict__ ws,
                    float* __restrict__ out) {
    __shared__ __align__(16) char smem[2608];
    int bx = blockIdx.x, tid = threadIdx.x;
    if (bx < 104) {
        int k = bx >> 3, b = bx & 7;
        float* F = (float*)smem;      // [512]
        float* ct = F + 512;          // [24]
        float* st = ct + 24;          // [24]
        if (tid < P_) {
            int r = (k * tid) % P_;
            float ph = 6.283185307179586f * (float)r / (float)P_;
            ct[tid] = cosf(ph);
            st[tid] = sinf(ph);
        }
        __syncthreads();
        {
            float fre = 0.f, fim = 0.f;
            for (int t = 0; t < P_; t++) {
                float v = ws[OFF_TE + (b * P_ + t) * D_ + tid];
                fre += ct[t] * v;
                fim -= st[t] * v;
            }
            F[tid] = fre;
            F[256 + tid] = fim;
        }
        __syncthreads();
        int o = tid;
        float acc = sfe_b1[k * 256 + o];
        const float* w1 = sfe_w1 + (long)k * 512 * 256;
        #pragma unroll 8
        for (int c = 0; c < 512; c++)
            acc += F[c] * w1[(long)c * 256 + o];
        ws[OFF_C1P + (long)(b * K_ + k) * 256 + o] = acc;
    } else if (bx < 616) {
        int j = bx - 104;
        int ntile = j & 63, b = j >> 6;
        int n = ntile * 16 + (tid >> 4), c = tid & 15;
        float gre[K_], gim[K_];
        #pragma unroll
        for (int k = 0; k < K_; k++) {
            gre[k] = ws[OFF_GAM + b * 32 + k];
            gim[k] = ws[OFF_GAM + b * 32 + 16 + k];
        }
        const ushort_t* xcp = (const ushort_t*)(ws + OFF_XC);
        int nt32 = n >> 5, halfn = (n >> 4) & 1, l15n = n & 15;
        int lre = ((c >> 3) * 16 + l15n) * 8 + (c & 7);
        int lim = ((2 + (c >> 3)) * 16 + l15n) * 8 + (c & 7);
        float acc = 0.f;
        #pragma unroll
        for (int k = 0; k < K_; k++) {
            long base = ((((long)(b * K_ + k) * 32 + nt32) * 2 + halfn) * 64) * 8;
            acc += gre[k] * bf2f(xcp[base + lre]) + gim[k] * bf2f(xcp[base + lim]);
        }
        ws[OFF_XW + ((long)b * N_ + n) * C_ + c] = acc;
    } else {
        int b = bx - 616;
        float* attl = (float*)smem;   // [24]
        if (tid < P_) attl[tid] = ws[OFF_ATT + b * P_ + tid];
        __syncthreads();
        float smn = 0.f, sa = 0.f;
        for (int t = 0; t < P_; t++) {
            float v = ws[OFF_TE + (b * P_ + t) * D_ + tid];
            smn += v;
            sa += attl[t] * v;
        }
        out[2097152 + b * D_ + tid] = smn * (1.0f / P_) - in_proj_b[tid];
        ws[OFF_ZWC + b * D_ + tid] = sa;
    }
}

// pack-stage for one k, 64-n tile: 9 global loads + 8 MFMA + gelu-pack.
// 4 XC n-halves share the AB fragments -> Dt amortization happens downstream.
__device__ __forceinline__ void pack_stage64(
        const float* __restrict__ ws, const ushort_t* __restrict__ xch,
        const ushort_t* __restrict__ abt, int b, int kk, int nt64,
        int wave, int lane, int oc0, int oc1, ushort4_t* w) {
    const ushort_t* xb = xch + (((long)(b * K_ + kk) * 32 + nt64 * 2) * 2) * 512 + lane * 8;
    bf16x8 pa0 = *(const bf16x8*)xb;
    bf16x8 pa1 = *(const bf16x8*)(xb + 512);
    bf16x8 pa2 = *(const bf16x8*)(xb + 1024);
    bf16x8 pa3 = *(const bf16x8*)(xb + 1536);
    const ushort_t* ab = abt + ((long)(kk * 8 + wave) * 2) * 512 + lane * 8;
    bf16x8 pb0 = *(const bf16x8*)ab;
    bf16x8 pb1 = *(const bf16x8*)(ab + 512);
    const float* cp = ws + OFF_C1P + (long)(b * K_ + kk) * 256;
    float4 c10 = *(const float4*)&cp[oc0];
    float4 c11 = *(const float4*)&cp[oc1];
    f32x4 p00 = {}, p01 = {}, p10 = {}, p11 = {};
    f32x4 p20 = {}, p21 = {}, p30 = {}, p31 = {};
    p00 = __builtin_amdgcn_mfma_f32_16x16x32_bf16(pb0, pa0, p00, 0, 0, 0);
    p01 = __builtin_amdgcn_mfma_f32_16x16x32_bf16(pb1, pa0, p01, 0, 0, 0);
    p10 = __builtin_amdgcn_mfma_f32_16x16x32_bf16(pb0, pa1, p10, 0, 0, 0);
    p11 = __builtin_amdgcn_mfma_f32_16x16x32_bf16(pb1, pa1, p11, 0, 0, 0);
    p20 = __builtin_amdgcn_mfma_f32_16x16x32_bf16(pb0, pa2, p20, 0, 0, 0);
    p21 = __builtin_amdgcn_mfma_f32_16x16x32_bf16(pb1, pa2, p21, 0, 0, 0);
    p30 = __builtin_amdgcn_mfma_f32_16x16x32_bf16(pb0, pa3, p30, 0, 0, 0);
    p31 = __builtin_amdgcn_mfma_f32_16x16x32_bf16(pb1, pa3, p31, 0, 0, 0);
    w[0] = pack4(p00, c10); w[1] = pack4(p01, c11);   // n-half 0 (rows 0-15)
    w[2] = pack4(p10, c10); w[3] = pack4(p11, c11);   // n-half 1 (rows 16-31)
    w[4] = pack4(p20, c10); w[5] = pack4(p21, c11);   // n-half 2 (rows 32-47)
    w[6] = pack4(p30, c10); w[7] = pack4(p31, c11);   // n-half 3 (rows 48-63)
}

// ==== k_final1: split-k(4) GEMM1 partial, 64n tile, 512 blocks (2/CU).
// 64n tile halves the Dt L2 stream (435MB -> 218MB): each Dt fragment
// in registers feeds 4 n-fragments instead of 2.
__global__ __launch_bounds__(512, 4) void k_final1(
        const float* __restrict__ ws, const ushort_t* __restrict__ xch,
        const ushort_t* __restrict__ abt, float* __restrict__ pacc) {
    int nt64 = blockIdx.x, b = blockIdx.y, kh = blockIdx.z;   // 16 x 8 x 4
    const int k0 = (kh == 0) ? 0 : 1 + 3 * kh;                // 0,4,7,10
    const int k1 = (kh == 0) ? 4 : k0 + 3;                    // 4,7,10,13
    int tid = threadIdx.x;
    int lane = tid & 63, wave = tid >> 6;
    int l15 = lane & 15, quad = lane >> 4;
    int wq0 = wave * 32;
    __shared__ ushort_t sl[64 * 264];    // 33792 B
    const ushort_t* dt = (const ushort_t*)(ws + OFF_DD);
    int oc0 = wq0 + quad * 4, oc1 = oc0 + 16;
    f32x4 acc00 = {}, acc01 = {}, acc10 = {}, acc11 = {};
    f32x4 acc20 = {}, acc21 = {}, acc30 = {}, acc31 = {};
    ushort4_t w[8];
    pack_stage64(ws, xch, abt, b, k0, nt64, wave, lane, oc0, oc1, w);
    for (int k = k0; k < k1; k++) {
        __syncthreads();
        *(ushort4_t*)&sl[(l15)      * 264 + oc0] = w[0];
        *(ushort4_t*)&sl[(l15)      * 264 + oc1] = w[1];
        *(ushort4_t*)&sl[(16 + l15) * 264 + oc0] = w[2];
        *(ushort4_t*)&sl[(16 + l15) * 264 + oc1] = w[3];
        *(ushort4_t*)&sl[(32 + l15) * 264 + oc0] = w[4];
        *(ushort4_t*)&sl[(32 + l15) * 264 + oc1] = w[5];
        *(ushort4_t*)&sl[(48 + l15) * 264 + oc0] = w[6];
        *(ushort4_t*)&sl[(48 + l15) * 264 + oc1] = w[7];
        __syncthreads();
        if (k + 1 < k1)
            pack_stage64(ws, xch, abt, b, k + 1, nt64, wave, lane, oc0, oc1, w);
        const ushort_t* dwb = dt + ((long)(k * 8 + wave) * 16) * 512 + lane * 8;
        #pragma unroll
        for (int s = 0; s < 8; s++) {
            int i0 = s * 32 + quad * 8;
            bf16x8 A0 = *(const bf16x8*)(dwb + s * 1024);
            bf16x8 A1 = *(const bf16x8*)(dwb + s * 1024 + 512);
            bf16x8 B0 = *(const bf16x8*)&sl[(l15)      * 264 + i0];
            bf16x8 B1 = *(const bf16x8*)&sl[(16 + l15) * 264 + i0];
            bf16x8 B2 = *(const bf16x8*)&sl[(32 + l15) * 264 + i0];
            bf16x8 B3 = *(const bf16x8*)&sl[(48 + l15) * 264 + i0];
            acc00 = __builtin_amdgcn_mfma_f32_16x16x32_bf16(A0, B0, acc00, 0, 0, 0);
            acc01 = __builtin_amdgcn_mfma_f32_16x16x32_bf16(A1, B0, acc01, 0, 0, 0);
            acc10 = __builtin_amdgcn_mfma_f32_16x16x32_bf16(A0, B1, acc10, 0, 0, 0);
            acc11 = __builtin_amdgcn_mfma_f32_16x16x32_bf16(A1, B1, acc11, 0, 0, 0);
            acc20 = __builtin_amdgcn_mfma_f32_16x16x32_bf16(A0, B2, acc20, 0, 0, 0);
            acc21 = __builtin_amdgcn_mfma_f32_16x16x32_bf16(A1, B2, acc21, 0, 0, 0);
            acc30 = __builtin_amdgcn_mfma_f32_16x16x32_bf16(A0, B3, acc30, 0, 0, 0);
            acc31 = __builtin_amdgcn_mfma_f32_16x16x32_bf16(A1, B3, acc31, 0, 0, 0);
        }
    }
    // store: pacc[kh][b][nt32][wave][{nh,och}][256]; nt32 = 2*nt64 + (h>>1), nh = h&1
    long base = ((((long)b * 32 + (nt64 << 1)) * 8 + wave) * 4) * 256 + lane * 4
              + (long)kh * KH_STRIDE;
    float* pp0 = pacc + base;               // nt32 = 2*nt64   (h=0,1)
    float* pp1 = pacc + base + 8 * 1024;    // nt32 = 2*nt64+1 (h=2,3); stride nt32 = 8*4*256
    *(float4*)(pp0 + 0)   = make_float4(acc00[0], acc00[1], acc00[2], acc00[3]);
    *(float4*)(pp0 + 512) = make_float4(acc01[0], acc01[1], acc01[2], acc01[3]);
    *(float4*)(pp0 + 256) = make_float4(acc10[0], acc10[1], acc10[2], acc10[3]);
    *(float4*)(pp0 + 768) = make_float4(acc11[0], acc11[1], acc11[2], acc11[3]);
    *(float4*)(pp1 + 0)   = make_float4(acc20[0], acc20[1], acc20[2], acc20[3]);
    *(float4*)(pp1 + 512) = make_float4(acc21[0], acc21[1], acc21[2], acc21[3]);
    *(float4*)(pp1 + 256) = make_float4(acc30[0], acc30[1], acc30[2], acc30[3]);
    *(float4*)(pp1 + 768) = make_float4(acc31[0], acc31[1], acc31[2], acc31[3]);
}

// ==== k_final2: sum 4 partials -> bias+gelu -> GEMM2 -> z, 32n tile ====
__global__ __launch_bounds__(512, 2) void k_final2(
        const float* __restrict__ ws, const float* __restrict__ pacc,
        const float* __restrict__ comb_b1, const float* __restrict__ comb_b2,
        float* __restrict__ out) {
    int ntile = blockIdx.x, b = blockIdx.y;  // 32 x 8
    int n0 = ntile * 32;
    int tid = threadIdx.x;
    int lane = tid & 63, wave = tid >> 6;
    int l15 = lane & 15, quad = lane >> 4;
    int wq0 = wave * 32;
    __shared__ ushort_t sh2[32 * 296];
    const ushort_t* w2e = (const ushort_t*)(ws + OFF_W2E);
    int oc0 = wq0 + quad * 4, oc1 = oc0 + 16;
    const float* pb = pacc + ((((long)b * 32 + ntile) * 8 + wave) * 4) * 256 + lane * 4;
    float4 s00 = *(const float4*)(pb + 0);
    float4 s01 = *(const float4*)(pb + 256);
    float4 s10 = *(const float4*)(pb + 512);
    float4 s11 = *(const float4*)(pb + 768);
    #pragma unroll
    for (int kh = 1; kh < 4; kh++) {
        const float* p = pb + (long)kh * KH_STRIDE;
        s00 = f4add(s00, *(const float4*)(p + 0));
        s01 = f4add(s01, *(const float4*)(p + 256));
        s10 = f4add(s10, *(const float4*)(p + 512));
        s11 = f4add(s11, *(const float4*)(p + 768));
    }
    float4 bc0 = *(const float4*)&comb_b1[oc0];
    float4 bc1 = *(const float4*)&comb_b1[oc1];
    #pragma unroll
    for (int k = 0; k < K_; k++) {
        bc0 = f4add(bc0, *(const float4*)&ws[OFF_BC + k * 256 + oc0]);
        bc1 = f4add(bc1, *(const float4*)&ws[OFF_BC + k * 256 + oc1]);
    }
    *(ushort4_t*)&sh2[l15 * 296 + oc0]        = pack4f(s00, bc0);
    *(ushort4_t*)&sh2[(16 + l15) * 296 + oc0] = pack4f(s01, bc0);
    *(ushort4_t*)&sh2[l15 * 296 + oc1]        = pack4f(s10, bc1);
    *(ushort4_t*)&sh2[(16 + l15) * 296 + oc1] = pack4f(s11, bc1);
    {
        int row = tid >> 4, cc = tid & 15;
        float xv = ws[OFF_XW + ((long)b * N_ + n0 + row) * C_ + cc];
        sh2[row * 296 + 256 + cc] = f2bf(xv);
        sh2[row * 296 + 272 + cc] = 0;
    }
    __syncthreads();
    f32x4 h00 = {}, h01 = {}, h10 = {}, h11 = {};
    #pragma unroll
    for (int s = 0; s < 9; s++) {
        int i0 = s * 32 + quad * 8;
        bf16x8 A0 = *(const bf16x8*)&w2e[(wq0 + l15) * 288 + i0];
        bf16x8 A1 = *(const bf16x8*)&w2e[(wq0 + 16 + l15) * 288 + i0];
        bf16x8 B0 = *(const bf16x8*)&sh2[l15 * 296 + i0];
        bf16x8 B1 = *(const bf16x8*)&sh2[(16 + l15) * 296 + i0];
        h00 = __builtin_amdgcn_mfma_f32_16x16x32_bf16(A0, B0, h00, 0, 0, 0);
        h01 = __builtin_amdgcn_mfma_f32_16x16x32_bf16(A0, B1, h01, 0, 0, 0);
        h10 = __builtin_amdgcn_mfma_f32_16x16x32_bf16(A1, B0, h10, 0, 0, 0);
        h11 = __builtin_amdgcn_mfma_f32_16x16x32_bf16(A1, B1, h11, 0, 0, 0);
    }
    float4 zc0 = *(const float4*)&ws[OFF_ZWC + b * 256 + oc0];
    float4 zc1 = *(const float4*)&ws[OFF_ZWC + b * 256 + oc1];
    float4 cb0 = *(const float4*)&comb_b2[oc0];
    float4 cb1 = *(const float4*)&comb_b2[oc1];
    long ob = ((long)b * N_ + n0) << 8;
    float4 o00, o01, o10, o11;
    o00.x = zc0.x + 0.3f * (h00[0] + cb0.x); o00.y = zc0.y + 0.3f * (h00[1] + cb0.y);
    o00.z = zc0.z + 0.3f * (h00[2] + cb0.z); o00.w = zc0.w + 0.3f * (h00[3] + cb0.w);
    o01.x = zc0.x + 0.3f * (h01[0] + cb0.x); o01.y = zc0.y + 0.3f * (h01[1] + cb0.y);
    o01.z = zc0.z + 0.3f * (h01[2] + cb0.z); o01.w = zc0.w + 0.3f * (h01[3] + cb0.w);
    o10.x = zc1.x + 0.3f * (h10[0] + cb1.x); o10.y = zc1.y + 0.3f * (h10[1] + cb1.y);
    o10.z = zc1.z + 0.3f * (h10[2] + cb1.z); o10.w = zc1.w + 0.3f * (h10[3] + cb1.w);
    o11.x = zc1.x + 0.3f * (h11[0] + cb1.x); o11.y = zc1.y + 0.3f * (h11[1] + cb1.y);
    o11.z = zc1.z + 0.3f * (h11[2] + cb1.z); o11.w = zc1.w + 0.3f * (h11[3] + cb1.w);
    *(float4*)&out[ob + ((long)l15 << 8) + oc0] = o00;
    *(float4*)&out[ob + ((long)(16 + l15) << 8) + oc0] = o01;
    *(float4*)&out[ob + ((long)l15 << 8) + oc1] = o10;
    *(float4*)&out[ob + ((long)(16 + l15) << 8) + oc1] = o11;
}

extern "C" void kernel_launch(void* const* d_in, const int* in_sizes, int n_in,
                              void* d_out, int out_size, void* d_ws, size_t ws_size,
                              hipStream_t stream) {
    const float* x = (const float*)d_in[0];
    const float* in_proj_w = (const float*)d_in[1];
    const float* in_proj_b = (const float*)d_in[2];
    const float* pe_w1 = (const float*)d_in[3];
    const float* pe_b1 = (const float*)d_in[4];
    const float* pe_w2 = (const float*)d_in[5];
    const float* pe_b2 = (const float*)d_in[6];
    const float* noise_w = (const float*)d_in[7];
    const float* noise_b = (const float*)d_in[8];
    const float* sfe_w1 = (const float*)d_in[9];
    const float* sfe_b1 = (const float*)d_in[10];
    const float* sfe_w2 = (const float*)d_in[11];
    const float* sfe_b2 = (const float*)d_in[12];
    const float* comb_w1 = (const float*)d_in[13];
    const float* comb_b1 = (const float*)d_in[14];
    const float* comb_w2 = (const float*)d_in[15];
    const float* comb_b2 = (const float*)d_in[16];
    const float* pool_param = (const float*)d_in[17];
    float* ws = (float*)d_ws;
    float* out = (float*)d_out;

    hipLaunchKernelGGL(k_A, dim3(2024), dim3(256), 0, stream,
                       x, in_proj_w, sfe_w1, sfe_w2, sfe_b2, comb_w1, comb_w2, ws);
    hipLaunchKernelGGL(k_B, dim3(226), dim3(128), 0, stream,
                       pool_param, pe_w1, pe_b1, pe_w2, pe_b2, noise_w, noise_b, in_proj_b, ws);
    hipLaunchKernelGGL(k_D, dim3(624), dim3(256), 0, stream, sfe_w1, sfe_b1, in_proj_b, ws, out);
    hipLaunchKernelGGL(k_final1, dim3(16, 8, 4), dim3(512), 0, stream,
                       ws, (const ushort_t*)(ws + OFF_XC), (const ushort_t*)(ws + OFF_AB),
                       ws + OFF_PACC);
    hipLaunchKernelGGL(k_final2, dim3(32, 8), dim3(512), 0, stream,
                       ws, ws + OFF_PACC, comb_b1, comb_b2, out);
}

// Round 10
// 211.738 us; speedup vs baseline: 1.0570x; 1.0570x over previous
//
#include <hip/hip_runtime.h>
#include <hip/hip_bf16.h>
#include <math.h>

#define B_ 8
#define P_ 24
#define N_ 1024
#define C_ 16
#define D_ 256
#define K_ 13

// workspace offsets (in floats)
#define OFF_SM   0          // spatial_mean: 192*16
#define OFF_ATT  8192       // att: 8*24
#define OFF_GAM  9216       // gamma: 8*32 (re[13] @ +0, im[13] @ +16)
#define OFF_TE   12288      // te_fold: 192*256
#define OFF_ZWC  122880     // zw_const: 8*256
#define OFF_AB   126976     // ABt bf16 FRAGMENT order [k][wave][half][lane][8]
#define OFF_BC   266240     // bias_comb: 13*256
#define OFF_DD   270336     // Dt bf16 FRAGMENT order [k][wave][s][half][lane][8]
#define OFF_W2E  696320     // W2ext bf16 [q2][288]
#define OFF_XC   1126400    // Xhat bf16 FRAGMENT order [b][k][nt32][half][lane][8]
#define OFF_XW   2830336    // xw fp32: 8*1024*16
#define OFF_ABP  3000000    // AB partials fp32 [k][et][32ch][256o]
#define OFF_C1P  3900000    // c1 REDUCED fp32 [b][k][256]
#define OFF_DLP  3930112    // d_lag partials: [b][4lag][24t][16chunk] = 12288
#define OFF_PACC 4194304    // GEMM1 split-k(2) partials fp32 [kh][b][nt][wave][4][256] (L2-resident)

typedef unsigned short ushort_t;
typedef __bf16 bf16x8 __attribute__((ext_vector_type(8)));
typedef float f32x4 __attribute__((ext_vector_type(4)));
typedef unsigned short ushort4_t __attribute__((ext_vector_type(4)));

__device__ __forceinline__ float gelu_f(float v) {
    return 0.5f * v * (1.0f + erff(v * 0.70710678118654752440f));
}
__device__ __forceinline__ float softplus_f(float z) {
    return fmaxf(z, 0.0f) + log1pf(expf(-fabsf(z)));
}
__device__ __forceinline__ ushort_t f2bf(float f) {
    union { float f; unsigned u; } v; v.f = f;
    unsigned r = v.u + 0x7fffu + ((v.u >> 16) & 1u);
    return (ushort_t)(r >> 16);
}
__device__ __forceinline__ float bf2f(ushort_t h) {
    union { unsigned u; float f; } v; v.u = ((unsigned)h) << 16;
    return v.f;
}
__device__ __forceinline__ float4 f4add(float4 a, float4 b) {
    a.x += b.x; a.y += b.y; a.z += b.z; a.w += b.w; return a;
}
__device__ __forceinline__ ushort4_t pack4(f32x4 v, float4 c) {
    ushort4_t w;
    w.x = f2bf(gelu_f(v[0] + c.x));
    w.y = f2bf(gelu_f(v[1] + c.y));
    w.z = f2bf(gelu_f(v[2] + c.z));
    w.w = f2bf(gelu_f(v[3] + c.w));
    return w;
}
__device__ __forceinline__ ushort4_t pack4f(float4 v, float4 c) {
    ushort4_t w;
    w.x = f2bf(gelu_f(v.x + c.x));
    w.y = f2bf(gelu_f(v.y + c.y));
    w.z = f2bf(gelu_f(v.z + c.z));
    w.w = f2bf(gelu_f(v.w + c.w));
    return w;
}

// ==== A: prep_d(832, dbuf) + xhat(512) + ab_part(104) + mean(192) + lag(128)
//      + w2e(256) = 2024 blocks, longest-first ====
__global__ void k_A(const float* __restrict__ x, const float* __restrict__ in_proj_w,
                    const float* __restrict__ sfe_w1, const float* __restrict__ sfe_w2,
                    const float* __restrict__ sfe_b2, const float* __restrict__ comb_w1,
                    const float* __restrict__ comb_w2, float* __restrict__ ws) {
    __shared__ __align__(16) char smem[8448];
    int bx = blockIdx.x, tid = threadIdx.x;
    if (bx < 832) {
        // prep_d: 32i x 32q tiles (8x8 x 13k), double-buffered As/Bs
        int j = bx;
        int qt0 = (j & 7) * 32, it3 = (j >> 3) & 7, k = j >> 6;
        int it0 = it3 * 32;
        float* sm0 = (float*)smem;   // 2 x (As 32*17 + Bs 16*32) = 2112 floats
        int tq = tid & 15, ti = tid >> 4;
        float acc[2][2];
        acc[0][0] = 0.f; acc[0][1] = 0.f; acc[1][0] = 0.f; acc[1][1] = 0.f;
        float bias = 0.f;
        {   // preload step 0 -> buf 0
            float* As = sm0; float* Bs = sm0 + 544;
            #pragma unroll
            for (int u = 0; u < 2; u++) {
                int idx = u * 256 + tid;
                int i = idx >> 4, o = idx & 15;
                As[i * 17 + o] = sfe_w2[((long)(k * 256 + it0 + i) << 8) + o];
            }
            #pragma unroll
            for (int u = 0; u < 2; u++) {
                int idx = u * 256 + tid;
                int o = idx >> 5, q = idx & 31;
                Bs[o * 32 + q] = comb_w1[((long)(k * 256 + o) << 8) + qt0 + q];
            }
        }
        __syncthreads();
        for (int step = 0; step < 16; step++) {
            int cur = step & 1;
            float* As = sm0 + cur * 1056;
            float* Bs = As + 544;
            if (step + 1 < 16) {
                int ob2 = (step + 1) * 16;
                float* An = sm0 + (cur ^ 1) * 1056;
                float* Bn = An + 544;
                #pragma unroll
                for (int u = 0; u < 2; u++) {
                    int idx = u * 256 + tid;
                    int i = idx >> 4, o = idx & 15;
                    An[i * 17 + o] = sfe_w2[((long)(k * 256 + it0 + i) << 8) + ob2 + o];
                }
                #pragma unroll
                for (int u = 0; u < 2; u++) {
                    int idx = u * 256 + tid;
                    int o = idx >> 5, q = idx & 31;
                    Bn[o * 32 + q] = comb_w1[((long)(k * 256 + ob2 + o) << 8) + qt0 + q];
                }
            }
            int ob = step * 16;
            if (it3 == 0 && tid < 32) {
                #pragma unroll
                for (int o = 0; o < 16; o++)
                    bias += sfe_b2[k * 256 + ob + o] * Bs[o * 32 + tid];
            }
            #pragma unroll 8
            for (int o = 0; o < 16; o++) {
                float2 bv = *(const float2*)&Bs[o * 32 + tq * 2];
                float a0 = As[(ti * 2 + 0) * 17 + o];
                float a1 = As[(ti * 2 + 1) * 17 + o];
                acc[0][0] += a0 * bv.x; acc[0][1] += a0 * bv.y;
                acc[1][0] += a1 * bv.x; acc[1][1] += a1 * bv.y;
            }
            __syncthreads();
        }
        ushort_t* dtp = (ushort_t*)(ws + OFF_DD);
        #pragma unroll
        for (int c = 0; c < 2; c++)
            #pragma unroll
            for (int r = 0; r < 2; r++) {
                int q = qt0 + tq * 2 + c, i = it0 + ti * 2 + r;
                int wv = q >> 5, hf = (q >> 4) & 1, l = q & 15;
                int s = i >> 5, qd = (i >> 3) & 3, jj = i & 7;
                long idx = ((((long)(k * 8 + wv) * 8 + s) * 2 + hf) * 64 + qd * 16 + l) * 8 + jj;
                dtp[idx] = f2bf(acc[r][c]);
            }
        if (it3 == 0 && tid < 32)
            ws[OFF_BC + k * 256 + qt0 + tid] = bias;
    } else if (bx < 1344) {
        // xhat DFT -> fragment-ordered xc2
        int j = bx - 832;
        int ntile = j & 63, b = j >> 6;
        float* ct = (float*)smem;
        float* st = ct + K_ * P_;
        int n = ntile * 16 + (tid >> 4), c = tid & 15;
        for (int i = tid; i < K_ * P_; i += 256) {
            int k = i / P_, t = i % P_;
            int r = (k * t) % P_;
            float ph = 6.283185307179586f * (float)r / (float)P_;
            ct[i] = cosf(ph);
            st[i] = sinf(ph);
        }
        __syncthreads();
        float re[K_], im[K_];
        #pragma unroll
        for (int k = 0; k < K_; k++) { re[k] = 0.f; im[k] = 0.f; }
        for (int t = 0; t < P_; t++) {
            float v = x[((long)(b * P_ + t) * N_ + n) * C_ + c];
            #pragma unroll
            for (int k = 0; k < K_; k++) {
                re[k] += ct[k * P_ + t] * v;
                im[k] -= st[k * P_ + t] * v;
            }
        }
        ushort_t* xcp = (ushort_t*)(ws + OFF_XC);
        int nt32 = n >> 5, halfn = (n >> 4) & 1, l15n = n & 15;
        int lre = ((c >> 3) * 16 + l15n) * 8 + (c & 7);
        int lim = ((2 + (c >> 3)) * 16 + l15n) * 8 + (c & 7);
        #pragma unroll
        for (int k = 0; k < K_; k++) {
            long base = ((((long)(b * K_ + k) * 32 + nt32) * 2 + halfn) * 64) * 8;
            xcp[base + lre] = f2bf(re[k]);
            xcp[base + lim] = f2bf(im[k]);
        }
    } else if (bx < 1448) {
        // ab_part
        int j = bx - 1344;
        int k = j >> 3, et = j & 7;
        int o = tid;
        float accA[C_], accB[C_];
        #pragma unroll
        for (int c = 0; c < C_; c++) { accA[c] = 0.f; accB[c] = 0.f; }
        const float* w1r = sfe_w1 + (long)k * 512 * 256;
        const float* w1i = w1r + 256 * 256;
        for (int e = et * 32; e < et * 32 + 32; e++) {
            float vr = w1r[e * 256 + o];
            float vi = w1i[e * 256 + o];
            #pragma unroll
            for (int c = 0; c < C_; c++) {
                float w = in_proj_w[c * 256 + e];
                accA[c] += w * vr;
                accB[c] += w * vi;
            }
        }
        float* abp = ws + OFF_ABP + (long)((k * 8 + et) * 32) * 256;
        #pragma unroll
        for (int c = 0; c < C_; c++) {
            abp[c * 256 + o] = accA[c];
            abp[(16 + c) * 256 + o] = accB[c];
        }
    } else if (bx < 1640) {
        // spatial mean
        float* lds = (float*)smem;
        int bt = bx - 1448;
        int c = tid & 15, ns = tid >> 4;
        const float* xp = x + (long)bt * (N_ * C_);
        float s = 0.f;
        for (int n = ns; n < N_; n += 16) s += xp[n * C_ + c];
        lds[tid] = s;
        __syncthreads();
        for (int st = 128; st >= 16; st >>= 1) {
            if (tid < st) lds[tid] += lds[tid + st];
            __syncthreads();
        }
        if (tid < 16) ws[OFF_SM + bt * 16 + tid] = lds[tid] * (1.0f / 1024.0f);
    } else if (bx < 1768) {
        // single-pass lag distances: 8b x 16 chunks, 4 cols/thread via float4
        int j = bx - 1640;
        int b = j >> 4, chunk = j & 15;
        int idx4 = (chunk << 8) + tid;    // float4 index in [0,4096)
        const float* xp = x + (long)b * (P_ * N_ * C_) + (idx4 << 2);
        float* sacc = (float*)smem;  // [4 waves][96]
        for (int i = tid; i < 384; i += 256) sacc[i] = 0.f;
        __syncthreads();
        int wave = tid >> 6, lane = tid & 63;
        float xh0[4] = {0.f,0.f,0.f,0.f}, xh1[4] = {0.f,0.f,0.f,0.f};
        float xr1[4] = {0.f,0.f,0.f,0.f}, xr2[4] = {0.f,0.f,0.f,0.f};
        float xr3[4] = {0.f,0.f,0.f,0.f}, xr4[4] = {0.f,0.f,0.f,0.f};
        float xr5[4] = {0.f,0.f,0.f,0.f}, xr6[4] = {0.f,0.f,0.f,0.f};
        #pragma unroll
        for (int t = 0; t < P_; t++) {
            float4 xq = *(const float4*)&xp[t * (N_ * C_)];
            float xv[4] = {xq.x, xq.y, xq.z, xq.w};
            float xr_t[4];
            #pragma unroll
            for (int j2 = 0; j2 < 4; j2++)
                xr_t[j2] = (t == 0) ? 0.f
                        : (t == 1) ? (xv[j2] - xh0[j2])
                        : (xv[j2] - (xv[j2] + xh0[j2] + xh1[j2]) * (1.0f / 3.0f));
            if (t >= 1) {
                float v0 = 0.f, v1 = 0.f, v2 = 0.f, v3 = 0.f;
                #pragma unroll
                for (int j2 = 0; j2 < 4; j2++) {
                    v0 += fabsf(xr_t[j2] - xr1[j2]);
                    if (t >= 2) v1 += fabsf(xr_t[j2] - xr2[j2]);
                    if (t >= 4) v2 += fabsf(xr_t[j2] - xr4[j2]);
                    if (t >= 6) v3 += fabsf(xr_t[j2] - xr6[j2]);
                }
                #pragma unroll
                for (int off = 32; off > 0; off >>= 1) {
                    v0 += __shfl_down(v0, off);
                    v1 += __shfl_down(v1, off);
                    v2 += __shfl_down(v2, off);
                    v3 += __shfl_down(v3, off);
                }
                if (lane == 0) {
                    float* sa = sacc + wave * 96 + t;
                    sa[0]  += v0;
                    sa[24] += v1;
                    sa[48] += v2;
                    sa[72] += v3;
                }
            }
            #pragma unroll
            for (int j2 = 0; j2 < 4; j2++) {
                xr6[j2] = xr5[j2]; xr5[j2] = xr4[j2]; xr4[j2] = xr3[j2];
                xr3[j2] = xr2[j2]; xr2[j2] = xr1[j2]; xr1[j2] = xr_t[j2];
                xh1[j2] = xh0[j2]; xh0[j2] = xv[j2];
            }
        }
        __syncthreads();
        if (tid < 96) {
            float s = sacc[tid] + sacc[96 + tid] + sacc[192 + tid] + sacc[288 + tid];
            int li = tid / 24, t = tid - li * 24;
            ws[OFF_DLP + ((b * 4 + li) * P_ + t) * 16 + chunk] = s;
        }
    } else {
        // W2ext
        int q2 = bx - 1768;
        ushort_t* w2e = (ushort_t*)(ws + OFF_W2E);
        for (int i = tid; i < 288; i += 256) {
            float v = 0.f;
            if (i < 256) v = comb_w2[(i << 8) + q2];
            else if (i < 272) v = in_proj_w[((i - 256) << 8) + q2] * (1.0f / 0.3f);
            w2e[q2 * 288 + i] = f2bf(v);
        }
    }
}

// ==== B: gating+gamma (8) + time_emb (192) + ab_red (26) = 226 blocks, 128 thr ====
__global__ void k_B(const float* __restrict__ pool_param,
                    const float* __restrict__ pe_w1, const float* __restrict__ pe_b1,
                    const float* __restrict__ pe_w2, const float* __restrict__ pe_b2,
                    const float* __restrict__ noise_w, const float* __restrict__ noise_b,
                    const float* __restrict__ in_proj_b, float* __restrict__ ws) {
    __shared__ float sm[256];
    int bx = blockIdx.x, tid = threadIdx.x;
    if (bx < 8) {
        int b = bx;
        float* d = sm; float* ad = sm + 96; float* med = sm + 192; float* mad = sm + 196;
        float* attb = sm + 200; float* gbuf = sm + 224;
        int li = tid / P_, t = tid - li * P_;
        bool active = tid < 4 * P_;
        if (active) {
            const float* dp = ws + OFF_DLP + ((b * 4 + li) * P_ + t) * 16;
            float4 q0 = *(const float4*)&dp[0];
            float4 q1 = *(const float4*)&dp[4];
            float4 q2 = *(const float4*)&dp[8];
            float4 q3 = *(const float4*)&dp[12];
            float s = q0.x + q0.y + q0.z + q0.w + q1.x + q1.y + q1.z + q1.w
                    + q2.x + q2.y + q2.z + q2.w + q3.x + q3.y + q3.z + q3.w;
            d[li * P_ + t] = s * (1.0f / (N_ * C_));
        }
        __syncthreads();
        if (active) {
            float v = d[li * P_ + t];
            int rank = 0;
            #pragma unroll
            for (int jj = 0; jj < P_; jj++) {
                float dj = d[li * P_ + jj];
                rank += (dj < v || (dj == v && jj < t)) ? 1 : 0;
            }
            if (rank == 11) med[li] = v;
        }
        __syncthreads();
        if (active) ad[li * P_ + t] = fabsf(d[li * P_ + t] - med[li]);
        __syncthreads();
        if (active) {
            float v = ad[li * P_ + t];
            int rank = 0;
            #pragma unroll
            for (int jj = 0; jj < P_; jj++) {
                float dj = ad[li * P_ + jj];
                rank += (dj < v || (dj == v && jj < t)) ? 1 : 0;
            }
            if (rank == 11) mad[li] = v;
        }
        __syncthreads();
        if (active) {
            float z = (d[li * P_ + t] - med[li]) / (mad[li] * 1.4826f + 1e-6f);
            ad[li * P_ + t] = softplus_f(z);
        }
        __syncthreads();
        if (tid == 0) {
            float g[P_];
            #pragma unroll
            for (int tt = 0; tt < P_; tt++)
                g[tt] = 0.25f * (ad[tt] + ad[P_ + tt] + ad[2 * P_ + tt] + ad[3 * P_ + tt]);
            float c = g[0];
            gbuf[0] = g[0];
            for (int tt = 1; tt < P_; tt++) { c = 0.6f * c + 0.4f * g[tt]; gbuf[tt] = c; }
            float mean = 0.f;
            for (int tt = 0; tt < P_; tt++) mean += gbuf[tt];
            mean *= (1.0f / P_);
            float gate[P_];
            #pragma unroll
            for (int tt = 0; tt < P_; tt++) gate[tt] = 1.0f / (1.0f + expf(-1.5f * (gbuf[tt] - mean)));
            float m = -1e30f;
            float pp[P_];
            #pragma unroll
            for (int tt = 0; tt < P_; tt++) { pp[tt] = pool_param[tt]; m = fmaxf(m, pp[tt]); }
            float ssum = 0.f;
            #pragma unroll
            for (int tt = 0; tt < P_; tt++) { pp[tt] = expf(pp[tt] - m); ssum += pp[tt]; }
            float m2 = -1e30f;
            #pragma unroll
            for (int tt = 0; tt < P_; tt++) { pp[tt] = (pp[tt] / ssum) * (1.0f + gate[tt]); m2 = fmaxf(m2, pp[tt]); }
            float s2 = 0.f;
            #pragma unroll
            for (int tt = 0; tt < P_; tt++) { pp[tt] = expf(pp[tt] - m2); s2 += pp[tt]; }
            #pragma unroll
            for (int tt = 0; tt < P_; tt++) {
                float a = pp[tt] / s2;
                ws[OFF_ATT + b * P_ + tt] = a;
                attb[tt] = a;
            }
        }
        __syncthreads();
        if (tid < K_) {
            int k = tid;
            float cre = 0.f, cim = 0.f;
            for (int t2 = 0; t2 < P_; t2++) {
                int r = (k * t2) % P_;
                float ph = 6.283185307179586f * (float)r / (float)P_;
                float a = attb[t2];
                cre += a * cosf(ph);
                cim += a * sinf(ph);
            }
            float w = (k == 0 || k == 12) ? 1.0f : 2.0f;
            ws[OFF_GAM + b * 32 + k] = (w / 24.0f) * cre;
            ws[OFF_GAM + b * 32 + 16 + k] = -(w / 24.0f) * cim;
        }
    } else if (bx < 200) {
        int bt = bx - 8;
        int t = bt % P_;
        int k = tid >> 6, o = tid & 63;
        float* p1e = sm;
        float period = (k == 0) ? 24.0f : 72.0f;
        float ph = 6.283185307179586f * (float)t / period;
        float sv = sinf(ph), cv = cosf(ph);
        float v = sv * pe_w1[(k * 2 + 0) * 64 + o] + cv * pe_w1[(k * 2 + 1) * 64 + o] + pe_b1[k * 64 + o];
        p1e[tid] = gelu_f(v);
        __syncthreads();
        float acc = pe_b2[k * 64 + o];
        for (int i = 0; i < 64; i++) acc += p1e[k * 64 + i] * pe_w2[(k * 64 + i) * 64 + o];
        ws[OFF_TE + bt * D_ + tid] = acc + in_proj_b[tid];
        float nacc = noise_b[tid];
        for (int c = 0; c < C_; c++) nacc += ws[OFF_SM + bt * C_ + c] * noise_w[c * 128 + tid];
        ws[OFF_TE + bt * D_ + 128 + tid] = nacc + in_proj_b[128 + tid];
    } else {
        // ab_red: reduce AB partials -> ABt fragment order (26 blocks x 128 thr)
        int j = bx - 200;
        int k = j >> 1, o = ((j & 1) << 7) + tid;
        ushort_t* abt = (ushort_t*)(ws + OFF_AB);
        const float* base = ws + OFF_ABP + (long)(k * 8 * 32) * 256;
        int wv = o >> 5, hf = (o >> 4) & 1, l = o & 15;
        long obase = (((long)(k * 8 + wv) * 2 + hf) * 64) * 8;
        #pragma unroll
        for (int ch = 0; ch < 32; ch++) {
            float s = 0.f;
            #pragma unroll
            for (int et = 0; et < 8; et++) s += base[(et * 32 + ch) * 256 + o];
            abt[obase + ((ch >> 3) * 16 + l) * 8 + (ch & 7)] = f2bf(s);
        }
    }
}

// ==== D: c1 with INLINE Fte-DFT (104) + xw (512) + te_reduce (8) = 624 blocks ====
__global__ void k_D(const float* __restrict__ sfe_w1, const float* __restrict__ sfe_b1,
                    const float* __restrict__ in_proj_b, float* __restrict__ ws,
                    float* __restrict__ out) {
    __shared__ __align__(16) char smem[2608];
    int bx = blockIdx.x, tid = threadIdx.x;
    if (bx < 104) {
        int k = bx >> 3, b = bx & 7;
        float* F = (float*)smem;      // [512]
        float* ct = F + 512;          // [24]
        float* st = ct + 24;          // [24]
        if (tid < P_) {
            int r = (k * tid) % P_;
            float ph = 6.283185307179586f * (float)r / (float)P_;
            ct[tid] = cosf(ph);
            st[tid] = sinf(ph);
        }
        __syncthreads();
        {
            float fre = 0.f, fim = 0.f;
            for (int t = 0; t < P_; t++) {
                float v = ws[OFF_TE + (b * P_ + t) * D_ + tid];
                fre += ct[t] * v;
                fim -= st[t] * v;
            }
            F[tid] = fre;
            F[256 + tid] = fim;
        }
        __syncthreads();
        int o = tid;
        float acc = sfe_b1[k * 256 + o];
        const float* w1 = sfe_w1 + (long)k * 512 * 256;
        #pragma unroll 8
        for (int c = 0; c < 512; c++)
            acc += F[c] * w1[(long)c * 256 + o];
        ws[OFF_C1P + (long)(b * K_ + k) * 256 + o] = acc;
    } else if (bx < 616) {
        int j = bx - 104;
        int ntile = j & 63, b = j >> 6;
        int n = ntile * 16 + (tid >> 4), c = tid & 15;
        float gre[K_], gim[K_];
        #pragma unroll
        for (int k = 0; k < K_; k++) {
            gre[k] = ws[OFF_GAM + b * 32 + k];
            gim[k] = ws[OFF_GAM + b * 32 + 16 + k];
        }
        const ushort_t* xcp = (const ushort_t*)(ws + OFF_XC);
        int nt32 = n >> 5, halfn = (n >> 4) & 1, l15n = n & 15;
        int lre = ((c >> 3) * 16 + l15n) * 8 + (c & 7);
        int lim = ((2 + (c >> 3)) * 16 + l15n) * 8 + (c & 7);
        float acc = 0.f;
        #pragma unroll
        for (int k = 0; k < K_; k++) {
            long base = ((((long)(b * K_ + k) * 32 + nt32) * 2 + halfn) * 64) * 8;
            acc += gre[k] * bf2f(xcp[base + lre]) + gim[k] * bf2f(xcp[base + lim]);
        }
        ws[OFF_XW + ((long)b * N_ + n) * C_ + c] = acc;
    } else {
        int b = bx - 616;
        float* attl = (float*)smem;   // [24]
        if (tid < P_) attl[tid] = ws[OFF_ATT + b * P_ + tid];
        __syncthreads();
        float smn = 0.f, sa = 0.f;
        for (int t = 0; t < P_; t++) {
            float v = ws[OFF_TE + (b * P_ + t) * D_ + tid];
            smn += v;
            sa += attl[t] * v;
        }
        out[2097152 + b * D_ + tid] = smn * (1.0f / P_) - in_proj_b[tid];
        ws[OFF_ZWC + b * D_ + tid] = sa;
    }
}

// pack-stage for one k (32-n tile): 6 global loads + 4 MFMA + gelu-pack
__device__ __forceinline__ void pack_stage(
        const float* __restrict__ ws, const ushort_t* __restrict__ xch,
        const ushort_t* __restrict__ abt, int b, int kk, int ntile,
        int wave, int lane, int oc0, int oc1, ushort4_t* w) {
    const ushort_t* xb = xch + (((long)(b * K_ + kk) * 32 + ntile) * 2) * 512 + lane * 8;
    bf16x8 pa0 = *(const bf16x8*)xb;
    bf16x8 pa1 = *(const bf16x8*)(xb + 512);
    const ushort_t* ab = abt + ((long)(kk * 8 + wave) * 2) * 512 + lane * 8;
    bf16x8 pb0 = *(const bf16x8*)ab;
    bf16x8 pb1 = *(const bf16x8*)(ab + 512);
    const float* cp = ws + OFF_C1P + (long)(b * K_ + kk) * 256;
    float4 c10 = *(const float4*)&cp[oc0];
    float4 c11 = *(const float4*)&cp[oc1];
    f32x4 p00 = {}, p01 = {}, p10 = {}, p11 = {};
    p00 = __builtin_amdgcn_mfma_f32_16x16x32_bf16(pb0, pa0, p00, 0, 0, 0);
    p01 = __builtin_amdgcn_mfma_f32_16x16x32_bf16(pb0, pa1, p01, 0, 0, 0);
    p10 = __builtin_amdgcn_mfma_f32_16x16x32_bf16(pb1, pa0, p10, 0, 0, 0);
    p11 = __builtin_amdgcn_mfma_f32_16x16x32_bf16(pb1, pa1, p11, 0, 0, 0);
    w[0] = pack4(p00, c10);
    w[1] = pack4(p01, c10);
    w[2] = pack4(p10, c11);
    w[3] = pack4(p11, c11);
}

// ==== k_final1: split-k(2) GEMM1 partial, 32n tile, 512 blocks (2/CU),
// DOUBLE-BUFFERED LDS P-tile: 1 barrier per k-iteration instead of 2.
__global__ __launch_bounds__(512, 4) void k_final1(
        const float* __restrict__ ws, const ushort_t* __restrict__ xch,
        const ushort_t* __restrict__ abt, float* __restrict__ pacc) {
    int ntile = blockIdx.x, b = blockIdx.y, kh = blockIdx.z;
    const int k0 = kh ? 7 : 0;
    const int k1 = kh ? K_ : 7;
    int tid = threadIdx.x;
    int lane = tid & 63, wave = tid >> 6;
    int l15 = lane & 15, quad = lane >> 4;
    int wq0 = wave * 32;
    __shared__ ushort_t sl[2][32 * 264];    // 2 x 16896 B
    const ushort_t* dt = (const ushort_t*)(ws + OFF_DD);
    int oc0 = wq0 + quad * 4, oc1 = oc0 + 16;
    f32x4 a00 = {}, a01 = {}, a10 = {}, a11 = {};
    ushort4_t w[4];
    pack_stage(ws, xch, abt, b, k0, ntile, wave, lane, oc0, oc1, w);
    {
        ushort_t* s0 = sl[0];
        *(ushort4_t*)&s0[l15 * 264 + oc0] = w[0];
        *(ushort4_t*)&s0[(16 + l15) * 264 + oc0] = w[1];
        *(ushort4_t*)&s0[l15 * 264 + oc1] = w[2];
        *(ushort4_t*)&s0[(16 + l15) * 264 + oc1] = w[3];
    }
    __syncthreads();
    int cur = 0;
    for (int k = k0; k < k1; k++) {
        if (k + 1 < k1)
            pack_stage(ws, xch, abt, b, k + 1, ntile, wave, lane, oc0, oc1, w);
        const ushort_t* sc = sl[cur];
        const ushort_t* dwb = dt + ((long)(k * 8 + wave) * 16) * 512 + lane * 8;
        #pragma unroll
        for (int s = 0; s < 8; s++) {
            int i0 = s * 32 + quad * 8;
            bf16x8 A0 = *(const bf16x8*)(dwb + s * 1024);
            bf16x8 A1 = *(const bf16x8*)(dwb + s * 1024 + 512);
            bf16x8 B0 = *(const bf16x8*)&sc[l15 * 264 + i0];
            bf16x8 B1 = *(const bf16x8*)&sc[(16 + l15) * 264 + i0];
            a00 = __builtin_amdgcn_mfma_f32_16x16x32_bf16(A0, B0, a00, 0, 0, 0);
            a01 = __builtin_amdgcn_mfma_f32_16x16x32_bf16(A0, B1, a01, 0, 0, 0);
            a10 = __builtin_amdgcn_mfma_f32_16x16x32_bf16(A1, B0, a10, 0, 0, 0);
            a11 = __builtin_amdgcn_mfma_f32_16x16x32_bf16(A1, B1, a11, 0, 0, 0);
        }
        if (k + 1 < k1) {
            ushort_t* sn = sl[cur ^ 1];
            *(ushort4_t*)&sn[l15 * 264 + oc0] = w[0];
            *(ushort4_t*)&sn[(16 + l15) * 264 + oc0] = w[1];
            *(ushort4_t*)&sn[l15 * 264 + oc1] = w[2];
            *(ushort4_t*)&sn[(16 + l15) * 264 + oc1] = w[3];
            __syncthreads();
        }
        cur ^= 1;
    }
    float* pp = pacc + ((((long)(kh * 8 + b) * 32 + ntile) * 8 + wave) * 4) * 256 + lane * 4;
    *(float4*)(pp + 0)   = make_float4(a00[0], a00[1], a00[2], a00[3]);
    *(float4*)(pp + 256) = make_float4(a01[0], a01[1], a01[2], a01[3]);
    *(float4*)(pp + 512) = make_float4(a10[0], a10[1], a10[2], a10[3]);
    *(float4*)(pp + 768) = make_float4(a11[0], a11[1], a11[2], a11[3]);
}

// ==== k_final2: sum 2 partials -> bias+gelu -> GEMM2 -> z, 32n tile ====
__global__ __launch_bounds__(512, 2) void k_final2(
        const float* __restrict__ ws, const float* __restrict__ pacc,
        const float* __restrict__ comb_b1, const float* __restrict__ comb_b2,
        float* __restrict__ out) {
    int ntile = blockIdx.x, b = blockIdx.y;  // 32 x 8
    int n0 = ntile * 32;
    int tid = threadIdx.x;
    int lane = tid & 63, wave = tid >> 6;
    int l15 = lane & 15, quad = lane >> 4;
    int wq0 = wave * 32;
    __shared__ ushort_t sh2[32 * 296];
    const ushort_t* w2e = (const ushort_t*)(ws + OFF_W2E);
    int oc0 = wq0 + quad * 4, oc1 = oc0 + 16;
    const float* p0 = pacc + ((((long)(0 * 8 + b) * 32 + ntile) * 8 + wave) * 4) * 256 + lane * 4;
    const float* p1 = pacc + ((((long)(1 * 8 + b) * 32 + ntile) * 8 + wave) * 4) * 256 + lane * 4;
    float4 s00 = f4add(*(const float4*)(p0 + 0),   *(const float4*)(p1 + 0));
    float4 s01 = f4add(*(const float4*)(p0 + 256), *(const float4*)(p1 + 256));
    float4 s10 = f4add(*(const float4*)(p0 + 512), *(const float4*)(p1 + 512));
    float4 s11 = f4add(*(const float4*)(p0 + 768), *(const float4*)(p1 + 768));
    float4 bc0 = *(const float4*)&comb_b1[oc0];
    float4 bc1 = *(const float4*)&comb_b1[oc1];
    #pragma unroll
    for (int k = 0; k < K_; k++) {
        bc0 = f4add(bc0, *(const float4*)&ws[OFF_BC + k * 256 + oc0]);
        bc1 = f4add(bc1, *(const float4*)&ws[OFF_BC + k * 256 + oc1]);
    }
    *(ushort4_t*)&sh2[l15 * 296 + oc0]        = pack4f(s00, bc0);
    *(ushort4_t*)&sh2[(16 + l15) * 296 + oc0] = pack4f(s01, bc0);
    *(ushort4_t*)&sh2[l15 * 296 + oc1]        = pack4f(s10, bc1);
    *(ushort4_t*)&sh2[(16 + l15) * 296 + oc1] = pack4f(s11, bc1);
    {
        int row = tid >> 4, cc = tid & 15;
        float xv = ws[OFF_XW + ((long)b * N_ + n0 + row) * C_ + cc];
        sh2[row * 296 + 256 + cc] = f2bf(xv);
        sh2[row * 296 + 272 + cc] = 0;
    }
    __syncthreads();
    f32x4 h00 = {}, h01 = {}, h10 = {}, h11 = {};
    #pragma unroll
    for (int s = 0; s < 9; s++) {
        int i0 = s * 32 + quad * 8;
        bf16x8 A0 = *(const bf16x8*)&w2e[(wq0 + l15) * 288 + i0];
        bf16x8 A1 = *(const bf16x8*)&w2e[(wq0 + 16 + l15) * 288 + i0];
        bf16x8 B0 = *(const bf16x8*)&sh2[l15 * 296 + i0];
        bf16x8 B1 = *(const bf16x8*)&sh2[(16 + l15) * 296 + i0];
        h00 = __builtin_amdgcn_mfma_f32_16x16x32_bf16(A0, B0, h00, 0, 0, 0);
        h01 = __builtin_amdgcn_mfma_f32_16x16x32_bf16(A0, B1, h01, 0, 0, 0);
        h10 = __builtin_amdgcn_mfma_f32_16x16x32_bf16(A1, B0, h10, 0, 0, 0);
        h11 = __builtin_amdgcn_mfma_f32_16x16x32_bf16(A1, B1, h11, 0, 0, 0);
    }
    float4 zc0 = *(const float4*)&ws[OFF_ZWC + b * 256 + oc0];
    float4 zc1 = *(const float4*)&ws[OFF_ZWC + b * 256 + oc1];
    float4 cb0 = *(const float4*)&comb_b2[oc0];
    float4 cb1 = *(const float4*)&comb_b2[oc1];
    long ob = ((long)b * N_ + n0) << 8;
    float4 o00, o01, o10, o11;
    o00.x = zc0.x + 0.3f * (h00[0] + cb0.x); o00.y = zc0.y + 0.3f * (h00[1] + cb0.y);
    o00.z = zc0.z + 0.3f * (h00[2] + cb0.z); o00.w = zc0.w + 0.3f * (h00[3] + cb0.w);
    o01.x = zc0.x + 0.3f * (h01[0] + cb0.x); o01.y = zc0.y + 0.3f * (h01[1] + cb0.y);
    o01.z = zc0.z + 0.3f * (h01[2] + cb0.z); o01.w = zc0.w + 0.3f * (h01[3] + cb0.w);
    o10.x = zc1.x + 0.3f * (h10[0] + cb1.x); o10.y = zc1.y + 0.3f * (h10[1] + cb1.y);
    o10.z = zc1.z + 0.3f * (h10[2] + cb1.z); o10.w = zc1.w + 0.3f * (h10[3] + cb1.w);
    o11.x = zc1.x + 0.3f * (h11[0] + cb1.x); o11.y = zc1.y + 0.3f * (h11[1] + cb1.y);
    o11.z = zc1.z + 0.3f * (h11[2] + cb1.z); o11.w = zc1.w + 0.3f * (h11[3] + cb1.w);
    *(float4*)&out[ob + ((long)l15 << 8) + oc0] = o00;
    *(float4*)&out[ob + ((long)(16 + l15) << 8) + oc0] = o01;
    *(float4*)&out[ob + ((long)l15 << 8) + oc1] = o10;
    *(float4*)&out[ob + ((long)(16 + l15) << 8) + oc1] = o11;
}

extern "C" void kernel_launch(void* const* d_in, const int* in_sizes, int n_in,
                              void* d_out, int out_size, void* d_ws, size_t ws_size,
                              hipStream_t stream) {
    const float* x = (const float*)d_in[0];
    const float* in_proj_w = (const float*)d_in[1];
    const float* in_proj_b = (const float*)d_in[2];
    const float* pe_w1 = (const float*)d_in[3];
    const float* pe_b1 = (const float*)d_in[4];
    const float* pe_w2 = (const float*)d_in[5];
    const float* pe_b2 = (const float*)d_in[6];
    const float* noise_w = (const float*)d_in[7];
    const float* noise_b = (const float*)d_in[8];
    const float* sfe_w1 = (const float*)d_in[9];
    const float* sfe_b1 = (const float*)d_in[10];
    const float* sfe_w2 = (const float*)d_in[11];
    const float* sfe_b2 = (const float*)d_in[12];
    const float* comb_w1 = (const float*)d_in[13];
    const float* comb_b1 = (const float*)d_in[14];
    const float* comb_w2 = (const float*)d_in[15];
    const float* comb_b2 = (const float*)d_in[16];
    const float* pool_param = (const float*)d_in[17];
    float* ws = (float*)d_ws;
    float* out = (float*)d_out;

    hipLaunchKernelGGL(k_A, dim3(2024), dim3(256), 0, stream,
                       x, in_proj_w, sfe_w1, sfe_w2, sfe_b2, comb_w1, comb_w2, ws);
    hipLaunchKernelGGL(k_B, dim3(226), dim3(128), 0, stream,
                       pool_param, pe_w1, pe_b1, pe_w2, pe_b2, noise_w, noise_b, in_proj_b, ws);
    hipLaunchKernelGGL(k_D, dim3(624), dim3(256), 0, stream, sfe_w1, sfe_b1, in_proj_b, ws, out);
    hipLaunchKernelGGL(k_final1, dim3(32, 8, 2), dim3(512), 0, stream,
                       ws, (const ushort_t*)(ws + OFF_XC), (const ushort_t*)(ws + OFF_AB),
                       ws + OFF_PACC);
    hipLaunchKernelGGL(k_final2, dim3(32, 8), dim3(512), 0, stream,
                       ws, ws + OFF_PACC, comb_b1, comb_b2, out);
}